// Round 9
// baseline (44.026 us; speedup 1.0000x reference)
//
#include <hip/hip_runtime.h>

typedef __bf16 bf16x8 __attribute__((ext_vector_type(8)));
typedef float  f32x16 __attribute__((ext_vector_type(16)));

#define NI 256
#define NT 256
#define NL 32
#define NE 128
#define HW 49
#define NEG_INF (-3.0e38f)

// ws layout (bf16), validated in R5/R8:
//  wsA: frag gw = (i*2+mt)*8+ks, elem (gw*64+lane)*8+j
//       = img[i, e=ks*16+(lane>>5)*8+j, hw=min(mt*32+(lane&31),48)]   (4 MB)
//  wsB: frag gw = t*8+ks, elem (gw*64+lane)*8+j
//       = txt[t, l=lane&31, e=ks*16+(lane>>5)*8+j]                    (2 MB)

// ---------- pre-kernel: fp32 -> bf16 MFMA-fragment layout ----------
__global__ __launch_bounds__(256, 4)
void prep_kernel(const float* __restrict__ img,
                 const float* __restrict__ txt,
                 __bf16* __restrict__ wsA,
                 __bf16* __restrict__ wsB)
{
    const int tid  = threadIdx.x;
    const int wave = tid >> 6, lane = tid & 63;
    const int ml   = lane & 31, h = lane >> 5;
    const int bid  = blockIdx.x;
    if (bid < 1024) {                       // A-part: 4096 waves
        int gw = bid * 4 + wave;            // (i, mt, ks)
        int i  = gw >> 4, mt = (gw >> 3) & 1, ks = gw & 7;
        int m  = mt * 32 + ml; if (m > HW - 1) m = HW - 1;
        int e0 = ks * 16 + h * 8;
        const float* p = img + ((size_t)i * NE + e0) * HW + m;
        union { __bf16 b[8]; int4 v; } u;
        #pragma unroll
        for (int j = 0; j < 8; ++j) u.b[j] = (__bf16)p[j * HW];
        *(int4*)(wsA + ((size_t)gw * 64 + lane) * 8) = u.v;
    } else {                                // B-part: 2048 waves
        int gw = (bid - 1024) * 4 + wave;   // (t, ks)
        int t  = gw >> 3, ks = gw & 7;
        int e0 = ks * 16 + h * 8;
        const float* p = txt + ((size_t)t * NL + ml) * NE + e0;
        float4 f0 = *(const float4*)p;
        float4 f1 = *(const float4*)(p + 4);
        union { __bf16 b[8]; int4 v; } u;
        u.b[0] = (__bf16)f0.x; u.b[1] = (__bf16)f0.y;
        u.b[2] = (__bf16)f0.z; u.b[3] = (__bf16)f0.w;
        u.b[4] = (__bf16)f1.x; u.b[5] = (__bf16)f1.y;
        u.b[6] = (__bf16)f1.z; u.b[7] = (__bf16)f1.w;
        *(int4*)(wsB + ((size_t)gw * 64 + lane) * 8) = u.v;
    }
}

// ---------- main kernel: ZERO barriers ----------
// Block: 4 waves; wave w owns TWO images (M=128): per text, 8 coalesced
// global dwordx4 B-loads (L2/L3-resident ws) -> 32 MFMA (F=4) -> tree-max.
// No B-LDS, no __syncthreads: waves free-run and de-phase, so matrix /
// VMEM / VALU pipes overlap across the 8 waves/CU instead of phase-locking.
// Grid 512 = 32 img-groups x 16 chunks (16 texts) = 2 blocks/CU, zero tail.
__global__ __launch_bounds__(256, 2)
void clip_match_kernel(const __bf16* __restrict__ wsA,
                       const __bf16* __restrict__ wsB,
                       const int* __restrict__ tlen,
                       const float* __restrict__ nlt,
                       float* __restrict__ out)
{
    const int tid  = threadIdx.x;
    const int wave = tid >> 6, lane = tid & 63;
    const int ml   = lane & 31, h = lane >> 5;
    const int tb   = blockIdx.x & 15;    // text chunk (16 texts)
    const int ig   = blockIdx.x >> 4;    // image group (8 images)

    const float scale = expf(nlt[0]);

    __shared__ __align__(16) float colmax[8][16][32];   // 16 KB, wave-private

    // ---- A fragments: 2 images, fragment-linear, 32 coalesced dwordx4 ----
    bf16x8 afrag[2][2][8];               // [img][mt][ks], 128 VGPRs
    {
        #pragma unroll
        for (int p = 0; p < 2; ++p) {
            int im = ig * 8 + wave * 2 + p;
            const __bf16* pa = wsA + (size_t)im * 2 * 8 * 512;
            #pragma unroll
            for (int mt = 0; mt < 2; ++mt)
                #pragma unroll
                for (int ks = 0; ks < 8; ++ks)
                    afrag[p][mt][ks] = *(const bf16x8*)(
                        pa + (size_t)((mt * 8 + ks) * 64 + lane) * 8);
        }
    }

    const __bf16* __restrict__ csrc = wsB + ((size_t)tb * 16 * 8 * 64 + lane) * 8;

    #pragma unroll 1
    for (int t = 0; t < 16; ++t) {
        // ---- B fragments for text t: 8 x global dwordx4, 1 KB/wave each ----
        bf16x8 bfrag[8];
        {
            const __bf16* pb = csrc + (size_t)t * 8 * 512;
            #pragma unroll
            for (int ks = 0; ks < 8; ++ks)
                bfrag[ks] = *(const bf16x8*)(pb + (size_t)ks * 512);
        }
        f32x16 acc[2][2];                // [img][mt]
        #pragma unroll
        for (int p = 0; p < 2; ++p)
            #pragma unroll
            for (int mt = 0; mt < 2; ++mt)
                acc[p][mt] = (f32x16)(0.f);
        #pragma unroll
        for (int ks = 0; ks < 8; ++ks) {
            acc[0][0] = __builtin_amdgcn_mfma_f32_32x32x16_bf16(
                afrag[0][0][ks], bfrag[ks], acc[0][0], 0, 0, 0);
            acc[0][1] = __builtin_amdgcn_mfma_f32_32x32x16_bf16(
                afrag[0][1][ks], bfrag[ks], acc[0][1], 0, 0, 0);
            acc[1][0] = __builtin_amdgcn_mfma_f32_32x32x16_bf16(
                afrag[1][0][ks], bfrag[ks], acc[1][0], 0, 0, 0);
            acc[1][1] = __builtin_amdgcn_mfma_f32_32x32x16_bf16(
                afrag[1][1][ks], bfrag[ks], acc[1][1], 0, 0, 0);
        }
        // per image: max over valid rows. C/D: col = lane&31,
        // row r2 = (reg&3)+8*(reg>>2)+4*h; mt0: m=r2 all valid;
        // mt1: m=32+r2 -> regs 0..7 valid, reg8 valid iff h==0 (m=48).
        #pragma unroll
        for (int p = 0; p < 2; ++p) {
            float t0[8];
            #pragma unroll
            for (int k = 0; k < 8; ++k)
                t0[k] = fmaxf(acc[p][0][2*k], acc[p][0][2*k+1]);
            float t1[4];
            #pragma unroll
            for (int k = 0; k < 4; ++k)
                t1[k] = fmaxf(t0[2*k], t0[2*k+1]);
            float a0m = fmaxf(fmaxf(t1[0], t1[1]), fmaxf(t1[2], t1[3]));
            float u0[4];
            #pragma unroll
            for (int k = 0; k < 4; ++k)
                u0[k] = fmaxf(acc[p][1][2*k], acc[p][1][2*k+1]);
            float a1m = fmaxf(fmaxf(u0[0], u0[1]), fmaxf(u0[2], u0[3]));
            float ex  = (h == 0) ? acc[p][1][8] : NEG_INF;
            float cm  = fmaxf(fmaxf(a0m, a1m), ex);
            cm = fmaxf(cm, __shfl_xor(cm, 32));   // merge h-halves
            if (h == 0) colmax[wave * 2 + p][t][ml] = cm;
        }
    }

    // ---- epilogue (wave-private colmax: same-wave LDS ordering suffices) ----
    {
        const int t = ml & 15;               // text within chunk
        const int p = ml >> 4;               // which of this wave's 2 images
        const float* row = &colmax[wave * 2 + p][t][h * 16];
        float4 a0 = *(const float4*)(row + 0);
        float4 a1 = *(const float4*)(row + 4);
        float4 a2 = *(const float4*)(row + 8);
        float4 a3 = *(const float4*)(row + 12);
        float s = ((a0.x + a0.y) + (a0.z + a0.w))
                + ((a1.x + a1.y) + (a1.z + a1.w))
                + ((a2.x + a2.y) + (a2.z + a2.w))
                + ((a3.x + a3.y) + (a3.z + a3.w));
        s += __shfl_xor(s, 32);              // both 16-col halves
        if (h == 0) {
            int tg = tb * 16 + t;
            int im = ig * 8 + wave * 2 + p;
            float v = s * scale / (float)tlen[tg];
            out[im * NT + tg] = v;              // logits_per_image[i,t]
            out[NI * NT + tg * NI + im] = v;    // logits_per_text[t,i]
        }
    }
}

extern "C" void kernel_launch(void* const* d_in, const int* in_sizes, int n_in,
                              void* d_out, int out_size, void* d_ws, size_t ws_size,
                              hipStream_t stream)
{
    const float* img  = (const float*)d_in[0];
    const float* txt  = (const float*)d_in[1];
    const int*   tlen = (const int*)d_in[2];
    const float* nlt  = (const float*)d_in[3];
    float* out = (float*)d_out;

    __bf16* wsA = (__bf16*)d_ws;                 // 4 MB
    __bf16* wsB = wsA + (size_t)4096 * 512;      // 2 MB

    prep_kernel<<<dim3(1536), dim3(256), 0, stream>>>(img, txt, wsA, wsB);
    clip_match_kernel<<<dim3(512), dim3(256), 0, stream>>>(wsA, wsB, tlen, nlt, out);
}

// Round 10
// 43.872 us; speedup vs baseline: 1.0035x; 1.0035x over previous
//
#include <hip/hip_runtime.h>

typedef __bf16 bf16x8 __attribute__((ext_vector_type(8)));
typedef float  f32x16 __attribute__((ext_vector_type(16)));

#define NI 256
#define NT 256
#define NL 32
#define NE 128
#define HW 49
#define NEG_INF (-3.0e38f)

// ws layout (bf16), validated in R5/R8:
//  wsA: frag gw = (i*2+mt)*8+ks, elem (gw*64+lane)*8+j
//       = img[i, e=ks*16+(lane>>5)*8+j, hw=min(mt*32+(lane&31),48)]   (4 MB)
//  wsB: frag gw = t*8+ks, elem (gw*64+lane)*8+j
//       = txt[t, l=lane&31, e=ks*16+(lane>>5)*8+j]                    (2 MB)

// ---------- pre-kernel: fp32 -> bf16 MFMA-fragment layout ----------
__global__ __launch_bounds__(256, 4)
void prep_kernel(const float* __restrict__ img,
                 const float* __restrict__ txt,
                 __bf16* __restrict__ wsA,
                 __bf16* __restrict__ wsB)
{
    const int tid  = threadIdx.x;
    const int wave = tid >> 6, lane = tid & 63;
    const int ml   = lane & 31, h = lane >> 5;
    const int bid  = blockIdx.x;
    if (bid < 1024) {                       // A-part: 4096 waves
        int gw = bid * 4 + wave;            // (i, mt, ks)
        int i  = gw >> 4, mt = (gw >> 3) & 1, ks = gw & 7;
        int m  = mt * 32 + ml; if (m > HW - 1) m = HW - 1;
        int e0 = ks * 16 + h * 8;
        const float* p = img + ((size_t)i * NE + e0) * HW + m;
        union { __bf16 b[8]; int4 v; } u;
        #pragma unroll
        for (int j = 0; j < 8; ++j) u.b[j] = (__bf16)p[j * HW];
        *(int4*)(wsA + ((size_t)gw * 64 + lane) * 8) = u.v;
    } else {                                // B-part: 2048 waves
        int gw = (bid - 1024) * 4 + wave;   // (t, ks)
        int t  = gw >> 3, ks = gw & 7;
        int e0 = ks * 16 + h * 8;
        const float* p = txt + ((size_t)t * NL + ml) * NE + e0;
        float4 f0 = *(const float4*)p;
        float4 f1 = *(const float4*)(p + 4);
        union { __bf16 b[8]; int4 v; } u;
        u.b[0] = (__bf16)f0.x; u.b[1] = (__bf16)f0.y;
        u.b[2] = (__bf16)f0.z; u.b[3] = (__bf16)f0.w;
        u.b[4] = (__bf16)f1.x; u.b[5] = (__bf16)f1.y;
        u.b[6] = (__bf16)f1.z; u.b[7] = (__bf16)f1.w;
        *(int4*)(wsB + ((size_t)gw * 64 + lane) * 8) = u.v;
    }
}

// ---------- main kernel: zero barriers + software-pipelined B ----------
// Block: 4 waves; wave owns TWO images (M=128). Per text: 8 global dwordx4
// B-loads (issued one text AHEAD, latency hidden under MFMA) -> 32 MFMA ->
// fmax tree -> per-half ds_write_b32 (no cross-lane op in the loop).
// Grid 512 = 32 img-groups x 16 chunks (16 texts) = 2 blocks/CU, zero tail.
__global__ __launch_bounds__(256, 2)
void clip_match_kernel(const __bf16* __restrict__ wsA,
                       const __bf16* __restrict__ wsB,
                       const int* __restrict__ tlen,
                       const float* __restrict__ nlt,
                       float* __restrict__ out)
{
    const int tid  = threadIdx.x;
    const int wave = tid >> 6, lane = tid & 63;
    const int ml   = lane & 31, h = lane >> 5;
    const int tb   = blockIdx.x & 15;    // text chunk (16 texts)
    const int ig   = blockIdx.x >> 4;    // image group (8 images)

    const float scale = expf(nlt[0]);

    // per-(img,text): 64 partial maxima (h*32+col), merged in epilogue
    __shared__ __align__(16) float colmax[8][16][64];   // 32 KB, wave-private

    // ---- A fragments: 2 images, fragment-linear, 32 coalesced dwordx4 ----
    bf16x8 afrag[2][2][8];               // [img][mt][ks], 128 VGPRs
    {
        #pragma unroll
        for (int p = 0; p < 2; ++p) {
            int im = ig * 8 + wave * 2 + p;
            const __bf16* pa = wsA + (size_t)im * 2 * 8 * 512;
            #pragma unroll
            for (int mt = 0; mt < 2; ++mt)
                #pragma unroll
                for (int ks = 0; ks < 8; ++ks)
                    afrag[p][mt][ks] = *(const bf16x8*)(
                        pa + (size_t)((mt * 8 + ks) * 64 + lane) * 8);
        }
    }

    const __bf16* __restrict__ csrc = wsB + ((size_t)tb * 16 * 8 * 64 + lane) * 8;

#define LOADB(dst, t)                                                      \
    {                                                                      \
        const __bf16* pb = csrc + (size_t)(t) * 4096;                      \
        _Pragma("unroll")                                                  \
        for (int ks = 0; ks < 8; ++ks)                                     \
            dst[ks] = *(const bf16x8*)(pb + (size_t)ks * 512);             \
    }

#define COMPUTE(bfr, t)                                                    \
    {                                                                      \
        f32x16 acc00 = (f32x16)(0.f), acc01 = (f32x16)(0.f);               \
        f32x16 acc10 = (f32x16)(0.f), acc11 = (f32x16)(0.f);               \
        _Pragma("unroll")                                                  \
        for (int ks = 0; ks < 8; ++ks) {                                   \
            acc00 = __builtin_amdgcn_mfma_f32_32x32x16_bf16(               \
                afrag[0][0][ks], bfr[ks], acc00, 0, 0, 0);                 \
            acc01 = __builtin_amdgcn_mfma_f32_32x32x16_bf16(               \
                afrag[0][1][ks], bfr[ks], acc01, 0, 0, 0);                 \
            acc10 = __builtin_amdgcn_mfma_f32_32x32x16_bf16(               \
                afrag[1][0][ks], bfr[ks], acc10, 0, 0, 0);                 \
            acc11 = __builtin_amdgcn_mfma_f32_32x32x16_bf16(               \
                afrag[1][1][ks], bfr[ks], acc11, 0, 0, 0);                 \
        }                                                                  \
        /* img 0: partial max over this h-half's rows; no cross-lane */    \
        {                                                                  \
            float t0[8];                                                   \
            _Pragma("unroll")                                              \
            for (int k = 0; k < 8; ++k)                                    \
                t0[k] = fmaxf(acc00[2*k], acc00[2*k+1]);                   \
            float t1[4];                                                   \
            _Pragma("unroll")                                              \
            for (int k = 0; k < 4; ++k) t1[k] = fmaxf(t0[2*k], t0[2*k+1]); \
            float a0m = fmaxf(fmaxf(t1[0], t1[1]), fmaxf(t1[2], t1[3]));   \
            float u0[4];                                                   \
            _Pragma("unroll")                                              \
            for (int k = 0; k < 4; ++k)                                    \
                u0[k] = fmaxf(acc01[2*k], acc01[2*k+1]);                   \
            float a1m = fmaxf(fmaxf(u0[0], u0[1]), fmaxf(u0[2], u0[3]));   \
            float ex  = (h == 0) ? acc01[8] : NEG_INF;                     \
            colmax[wave * 2 + 0][t][lane] = fmaxf(fmaxf(a0m, a1m), ex);    \
        }                                                                  \
        /* img 1 */                                                        \
        {                                                                  \
            float t0[8];                                                   \
            _Pragma("unroll")                                              \
            for (int k = 0; k < 8; ++k)                                    \
                t0[k] = fmaxf(acc10[2*k], acc10[2*k+1]);                   \
            float t1[4];                                                   \
            _Pragma("unroll")                                              \
            for (int k = 0; k < 4; ++k) t1[k] = fmaxf(t0[2*k], t0[2*k+1]); \
            float a0m = fmaxf(fmaxf(t1[0], t1[1]), fmaxf(t1[2], t1[3]));   \
            float u0[4];                                                   \
            _Pragma("unroll")                                              \
            for (int k = 0; k < 4; ++k)                                    \
                u0[k] = fmaxf(acc11[2*k], acc11[2*k+1]);                   \
            float a1m = fmaxf(fmaxf(u0[0], u0[1]), fmaxf(u0[2], u0[3]));   \
            float ex  = (h == 0) ? acc11[8] : NEG_INF;                     \
            colmax[wave * 2 + 1][t][lane] = fmaxf(fmaxf(a0m, a1m), ex);    \
        }                                                                  \
    }

    bf16x8 b0[8], b1[8];
    LOADB(b0, 0)
    #pragma unroll 1
    for (int it = 0; it < 8; ++it) {
        const int t = it * 2;
        LOADB(b1, t + 1)                 // prefetch: hides under COMPUTE(b0)
        COMPUTE(b0, t)
        if (it < 7) LOADB(b0, t + 2)     // prefetch: hides under COMPUTE(b1)
        COMPUTE(b1, t + 1)
    }
#undef LOADB
#undef COMPUTE

    // ---- epilogue: merge h-halves, sum 32 cols, write both mirrors ----
    {
        const int t = ml & 15;               // text within chunk
        const int p = ml >> 4;               // which of this wave's 2 images
        const float* row = &colmax[wave * 2 + p][t][0];
        const float* r0 = row + h * 16;      // this half's 16 cols, h-part 0
        const float* r1 = row + 32 + h * 16; // h-part 1
        float4 a0 = *(const float4*)(r0 + 0);
        float4 a1 = *(const float4*)(r0 + 4);
        float4 a2 = *(const float4*)(r0 + 8);
        float4 a3 = *(const float4*)(r0 + 12);
        float4 c0 = *(const float4*)(r1 + 0);
        float4 c1 = *(const float4*)(r1 + 4);
        float4 c2 = *(const float4*)(r1 + 8);
        float4 c3 = *(const float4*)(r1 + 12);
        float s = (fmaxf(a0.x, c0.x) + fmaxf(a0.y, c0.y))
                + (fmaxf(a0.z, c0.z) + fmaxf(a0.w, c0.w))
                + (fmaxf(a1.x, c1.x) + fmaxf(a1.y, c1.y))
                + (fmaxf(a1.z, c1.z) + fmaxf(a1.w, c1.w))
                + (fmaxf(a2.x, c2.x) + fmaxf(a2.y, c2.y))
                + (fmaxf(a2.z, c2.z) + fmaxf(a2.w, c2.w))
                + (fmaxf(a3.x, c3.x) + fmaxf(a3.y, c3.y))
                + (fmaxf(a3.z, c3.z) + fmaxf(a3.w, c3.w));
        s += __shfl_xor(s, 32);              // both 16-col halves
        if (h == 0) {
            int tg = tb * 16 + t;
            int im = ig * 8 + wave * 2 + p;
            float v = s * scale / (float)tlen[tg];
            out[im * NT + tg] = v;              // logits_per_image[i,t]
            out[NI * NT + tg * NI + im] = v;    // logits_per_text[t,i]
        }
    }
}

extern "C" void kernel_launch(void* const* d_in, const int* in_sizes, int n_in,
                              void* d_out, int out_size, void* d_ws, size_t ws_size,
                              hipStream_t stream)
{
    const float* img  = (const float*)d_in[0];
    const float* txt  = (const float*)d_in[1];
    const int*   tlen = (const int*)d_in[2];
    const float* nlt  = (const float*)d_in[3];
    float* out = (float*)d_out;

    __bf16* wsA = (__bf16*)d_ws;                 // 4 MB
    __bf16* wsB = wsA + (size_t)4096 * 512;      // 2 MB

    prep_kernel<<<dim3(1536), dim3(256), 0, stream>>>(img, txt, wsA, wsB);
    clip_match_kernel<<<dim3(512), dim3(256), 0, stream>>>(wsA, wsB, tlen, nlt, out);
}